// Round 1
// baseline (125.108 us; speedup 1.0000x reference)
//
#include <hip/hip_runtime.h>
#include <cstdint>
#include <cstddef>

// EcoAttention: block-local top-p truncated attention, S=4096 D=128 BLOCK=64.
//
// R11 = R10 with the bitonic sort replaced by max-peeling.
//  - The sorted-cumsum mask only needs the scalar t = #positions with
//    cum < 0.95*s; kept weights are the FIRST-t keys in original order.
//    Scores are N(0,128)-ish -> exp mass is dominated by the top element
//    (which is exactly 1.0 after max-subtraction), so t is typically 0..3.
//    Peel: iter0 uses M=1.0 for free; each further iter = 16-elem max3 tree
//    + 2 shfl + predicated removal. Replaces ~700 serial VALU + ~50 shfl
//    of bitonic sort with ~50 VALU + 2 shfl per iteration, ~3-6 iters/wave.
//  - MFMA(K,Q): C col(=lane&15) is the Q-row -> each lane holds 16 scores of
//    ONE Q-row (K idx = nt*16+quad*4+rg). Peel runs register-direct.
//  - LDS = 32KB K-planes + 8KB weight scratch = 40KB -> 4 WG/CU; grid
//    1024 = exactly 4/CU, no tail; __launch_bounds__(256,4).
//  - prep: LDS-free, 256 WGs (coalesced K-split + Vt-frag emission +
//    distributed O zeroing).

#define SEQ   4096
#define DIM   128
#define BLK   64
#define NB    (SEQ / BLK)   // 64
#define NJG   16            // j-groups (1024 WGs)
#define JPB   (NB / NJG)    // 4 key blocks per WG
#define NT    256
#define PSTR  12288         // uints per prepped block (Khi 16KB | Kr 16KB | Vt 16KB)
#define THRESH 0.95f
#define EPSF   1e-8f

typedef __attribute__((ext_vector_type(8))) _Float16 f16x8;
typedef __attribute__((ext_vector_type(4))) float    f32x4;

#define MFMAH(a, b, c) __builtin_amdgcn_mfma_f32_16x16x32_f16((a), (b), (c), 0, 0, 0)

union UH4 { uint2 u; _Float16 h[4]; };
union UH8 { uint4 u; f16x8 v; };

__device__ __forceinline__ void gll16(const uint* g, uint* l) {
  __builtin_amdgcn_global_load_lds(
      (const __attribute__((address_space(1))) void*)g,
      (__attribute__((address_space(3))) void*)l, 16, 0, 0);
}

// ---- prep: LDS-free, 4 WGs per key block. Builds [Khi|Kr|Vt-frag] 48KB
//      images in d_ws and zeroes O. ----
__global__ __launch_bounds__(NT, 4) void eco_prep_kernel(
    const float* __restrict__ K, const float* __restrict__ V,
    uint* __restrict__ P, float* __restrict__ O) {
  const int tid  = threadIdx.x;
  const int b    = blockIdx.x;     // 0..255
  const int jb   = b >> 2;
  const int part = b & 3;

  // zero O slice (2MB spread over 256 WGs)
  {
    float4 z = {0.f, 0.f, 0.f, 0.f};
    float4* op = (float4*)O;
#pragma unroll
    for (int it = 0; it < 2; ++it) op[b * 512 + it * NT + tid] = z;
  }

  // K 2-term f16 split -> swizzled planes (element (r,c): chunk=c/8,
  // uint off r*64 + ((chunk ^ (r&15))*4) + (c%8)/2); 2048 float4 per block.
  {
    const float4* gk = (const float4*)(K + (size_t)jb * BLK * DIM);
    uint* dst = P + (size_t)jb * PSTR;
#pragma unroll
    for (int it = 0; it < 2; ++it) {
      int f = part * 512 + it * NT + tid;   // float4 idx 0..2047
      int r = f >> 5, c4 = f & 31;
      float4 x = gk[f];
      float xs[4] = {x.x, x.y, x.z, x.w};
      UH4 uh, ur;
#pragma unroll
      for (int e = 0; e < 4; ++e) {
        float v = xs[e];
        _Float16 h = (_Float16)v;
        uh.h[e] = h;
        ur.h[e] = (_Float16)(v - (float)h);   // exact residual (Sterbenz)
      }
      uint off = (uint)r * 64u + (((uint)(c4 >> 1) ^ (uint)(r & 15)) << 2) +
                 (uint)((c4 & 1) << 1);
      *(uint2*)&dst[off]        = uh.u;
      *(uint2*)&dst[4096 + off] = ur.u;
    }
  }

  // Vt in PV B-frag linear order: ONLY 1024 fragments (ch in [0,8), d in
  // [0,128)); frag idx = ch*128 + d, 8 f16 = V[ch*8+j][d]. One frag/thread.
  {
    const float* gv = V + (size_t)jb * BLK * DIM;
    uint4* dv = (uint4*)(P + (size_t)jb * PSTR + 8192);
    int idx = part * 256 + tid;            // frag idx 0..1023
    int ch = idx >> 7, d = idx & 127;
    UH8 u;
#pragma unroll
    for (int j = 0; j < 8; ++j)
      u.v[j] = (_Float16)gv[(ch * 8 + j) * DIM + d];
    dv[idx] = u.u;
  }
}

__global__ __launch_bounds__(NT, 4) void eco_attn_kernel(
    const float* __restrict__ Q, const uint* __restrict__ P,
    float* __restrict__ O) {
  __shared__ __align__(16) uint sK[8192];   // 32 KB: Khi / Kr planes
  __shared__ __align__(16) uint sW[2048];   // 8 KB: 4 x (16 rows x 32 uints)

  const int tid  = threadIdx.x;
  const int ib   = blockIdx.y;
  const int jg   = blockIdx.x;
  const int lane = tid & 63;
  const int wv   = tid >> 6;
  const int quad = lane >> 4;   // 0..3
  const int l16  = lane & 15;
  const int q4   = quad << 2;

  uint* sWw = sW + wv * 512;    // this wave's weight rows (16 x 32 uints)

  // ---- Q fragments (B-operand now): q-row = wv*16+l16, k = ks*32+quad*8+j ----
  f16x8 qh[4], qr[4];
  {
    const float* qp = Q + (size_t)(ib * BLK + wv * 16 + l16) * DIM + quad * 8;
#pragma unroll
    for (int ks = 0; ks < 4; ++ks) {
      float4 x0 = *(const float4*)(qp + ks * 32);
      float4 x1 = *(const float4*)(qp + ks * 32 + 4);
      float xs[8] = {x0.x, x0.y, x0.z, x0.w, x1.x, x1.y, x1.z, x1.w};
      f16x8 h8, r8;
#pragma unroll
      for (int e = 0; e < 8; ++e) {
        float v = xs[e];
        _Float16 h = (_Float16)v;
        h8[e] = h;
        r8[e] = (_Float16)(v - (float)h);
      }
      qh[ks] = h8; qr[ks] = r8;
    }
  }

  const f32x4 zf = {0.f, 0.f, 0.f, 0.f};
  f32x4 pv[8];
#pragma unroll
  for (int i = 0; i < 8; ++i) pv[i] = zf;

  // prologue: stage first K image (32KB = 8 x 16B per thread)
  {
    const uint* gsrc = P + (size_t)(jg * JPB) * PSTR;
#pragma unroll
    for (int it = 0; it < 8; ++it) {
      int idx = (it * NT + tid) << 2;
      gll16(gsrc + idx, sK + idx);
    }
  }

  for (int jj = 0; jj < JPB; ++jj) {
    const int jb = jg * JPB + jj;
    __syncthreads();  // B1: K image staged (vmcnt drained by barrier)

    // ---- QK^T, operand-swapped: A = K (from LDS), B = Q (resident) ----
    // C: col(l16) = Q-row (wv*16+l16), row(quad*4+reg) = K-row nt*16+quad*4+reg
    f32x4 ah[4], ar[4];
#pragma unroll
    for (int nt = 0; nt < 4; ++nt) { ah[nt] = zf; ar[nt] = zf; }
#pragma unroll
    for (int nt = 0; nt < 4; ++nt) {
      const int rB = nt * 16 + l16;      // K-row for the A-frag read
      const uint rowoff = (uint)rB * 64u;
      const uint swk = (uint)(rB & 15);
#pragma unroll
      for (int ks = 0; ks < 4; ++ks) {
        uint off = rowoff + ((((uint)(ks * 4 + quad)) ^ swk) << 2);
        f16x8 bh = *(const f16x8*)&sK[off];
        f16x8 br = *(const f16x8*)&sK[4096 + off];
        ah[nt] = MFMAH(bh, qh[ks], ah[nt]);
        ar[nt] = MFMAH(br, qh[ks], ar[nt]);
        ar[nt] = MFMAH(bh, qr[ks], ar[nt]);
      }
    }
    __syncthreads();  // B0: all waves done reading sK

    // ---- prefetch next K image (overlaps peel + PV below) ----
    if (jj + 1 < JPB) {
      const uint* gsrc = P + (size_t)(jb + 1) * PSTR;
#pragma unroll
      for (int it = 0; it < 8; ++it) {
        int idx = (it * NT + tid) << 2;
        gll16(gsrc + idx, sK + idx);
      }
    }

    // ---- top-p softmax, register-direct: this lane owns Q-row wv*16+l16;
    //      a[i] (i = nt*4+rg) is score at K-index nt*16 + q4 + rg ----
    {
      float a[16], e[16];
#pragma unroll
      for (int nt = 0; nt < 4; ++nt) {
        f32x4 s = ah[nt] + ar[nt];
#pragma unroll
        for (int rg = 0; rg < 4; ++rg) a[nt * 4 + rg] = s[rg];
      }
      // row max: local tree + cross-quad (lanes l16, l16+16, +32, +48)
      float mt[8];
#pragma unroll
      for (int i = 0; i < 8; ++i) mt[i] = fmaxf(a[i], a[i + 8]);
#pragma unroll
      for (int w2 = 4; w2 >= 1; w2 >>= 1)
#pragma unroll
        for (int i = 0; i < w2; ++i) mt[i] = fmaxf(mt[i], mt[i + w2]);
      float m = mt[0];
      m = fmaxf(m, __shfl_xor(m, 16, 64));
      m = fmaxf(m, __shfl_xor(m, 32, 64));
#pragma unroll
      for (int i = 0; i < 16; ++i) { a[i] = __expf(a[i] - m); e[i] = a[i]; }
      float st[8];
#pragma unroll
      for (int i = 0; i < 8; ++i) st[i] = a[i] + a[i + 8];
#pragma unroll
      for (int w2 = 4; w2 >= 1; w2 >>= 1)
#pragma unroll
        for (int i = 0; i < w2; ++i) st[i] += st[i + w2];
      float sr = st[0];
      sr += __shfl_xor(sr, 16, 64);
      sr += __shfl_xor(sr, 32, 64);
      const float T = THRESH * sr;

      // ---- t via max-peeling (replaces bitonic sort).
      //      t = #{sorted positions j : cum_j < T}, cum_j built in exact
      //      descending sequential order (matches reference association).
      //      Iter 0: the max exp is exactly 1.0f -> no reduce needed.
      float cum = 1.0f;
      bool live = (cum < T);           // this row still peeling?
      int t = live ? 1 : 0;
#pragma unroll
      for (int i = 0; i < 16; ++i) a[i] = (a[i] >= 1.0f) ? 0.f : a[i];
      while (__any(live)) {
        // max of remaining 64 (16 regs x 4 quad-lanes); fmaxf triples -> v_max3
        float M = fmaxf(fmaxf(fmaxf(a[0], a[1]), a[2]),
                        fmaxf(fmaxf(a[3], a[4]), a[5]));
        M = fmaxf(M, fmaxf(fmaxf(a[6],  a[7]),  a[8]));
        M = fmaxf(M, fmaxf(fmaxf(a[9],  a[10]), a[11]));
        M = fmaxf(M, fmaxf(fmaxf(a[12], a[13]), a[14]));
        M = fmaxf(M, a[15]);
        M = fmaxf(M, __shfl_xor(M, 16, 64));
        M = fmaxf(M, __shfl_xor(M, 32, 64));
        const float cn = cum + M;
        // stop when crossing the threshold, or safety: nothing left (M<=0)
        const bool cross = !(cn < T) || !(M > 0.f);
        if (live) {
          cum = cn;
          t += cross ? 0 : 1;
        }
        live = live && !cross;
        // remove the peeled max (ties collapse; bit-exact f32 score ties
        // are measure-zero for this data)
#pragma unroll
        for (int i = 0; i < 16; ++i) a[i] = (a[i] >= M) ? 0.f : a[i];
      }

      // renormalize first-t (ORIGINAL K order; kidx = nt*16 + q4 + rg)
      float p = 0.f;
#pragma unroll
      for (int i = 0; i < 16; ++i) {
        int kidx = ((i >> 2) << 4) + q4 + (i & 3);
        p += (kidx < t) ? e[i] : 0.f;
      }
      p += __shfl_xor(p, 16, 64);
      p += __shfl_xor(p, 32, 64);
      const float rn = 1.0f / (p + EPSF);
      // emit f16 weights: row l16, 16 chunks of 4 f16; chunk c4 = nt*4+quad
      // at swizzled uint offset row*32 + ((c4 ^ row) << 1)
      uint* wrow = sWw + l16 * 32;
#pragma unroll
      for (int nt = 0; nt < 4; ++nt) {
        UH4 u;
#pragma unroll
        for (int rg = 0; rg < 4; ++rg) {
          int kidx = nt * 16 + q4 + rg;
          float w = (kidx < t) ? e[nt * 4 + rg] * rn : 0.f;
          u.h[rg] = (_Float16)w;
        }
        uint c4 = (uint)(nt * 4 + quad);
        *(uint2*)&wrow[(c4 ^ (uint)l16) << 1] = u.u;
      }
    }
    __builtin_amdgcn_wave_barrier();  // weight writes before A-frag reads

    // ---- PV: A = f16 weights (wave-private LDS), B = Vt-frag from global ----
    f16x8 wf[2];
#pragma unroll
    for (int ks2 = 0; ks2 < 2; ++ks2) {
      uint c0 = (uint)(ks2 * 8 + quad * 2);
      const uint* wrow = sWw + l16 * 32;
      uint2 lo = *(const uint2*)&wrow[(c0 ^ (uint)l16) << 1];
      uint2 hi = *(const uint2*)&wrow[((c0 + 1) ^ (uint)l16) << 1];
      UH8 u;
      u.u = make_uint4(lo.x, lo.y, hi.x, hi.y);
      wf[ks2] = u.v;
    }
    {
      const uint* gvt = P + (size_t)jb * PSTR + 8192;
#pragma unroll
      for (int nt2 = 0; nt2 < 8; ++nt2) {
#pragma unroll
        for (int ks2 = 0; ks2 < 2; ++ks2) {
          f16x8 vf = *(const f16x8*)&gvt[((uint)((ks2 * 4 + quad) * 128 +
                                                 nt2 * 16 + l16)) << 2];
          pv[nt2] = MFMAH(wf[ks2], vf, pv[nt2]);
        }
      }
    }
  }

  // ---- epilogue: C-layout -> global atomicAdd over the 16 j-groups ----
#pragma unroll
  for (int nt2 = 0; nt2 < 8; ++nt2) {
    const int col  = nt2 * 16 + l16;
    const int row0 = ib * BLK + wv * 16 + quad * 4;
#pragma unroll
    for (int rg = 0; rg < 4; ++rg)
      atomicAdd(O + (size_t)(row0 + rg) * DIM + col, pv[nt2][rg]);
  }
}

extern "C" void kernel_launch(void* const* d_in, const int* in_sizes, int n_in,
                              void* d_out, int out_size, void* d_ws, size_t ws_size,
                              hipStream_t stream) {
  (void)in_sizes; (void)n_in; (void)ws_size; (void)out_size;
  const float* q = (const float*)d_in[0];
  const float* k = (const float*)d_in[1];
  const float* v = (const float*)d_in[2];
  float* out = (float*)d_out;
  uint* prep = (uint*)d_ws;   // 64 blocks x 48 KB = 3 MB

  eco_prep_kernel<<<dim3(NB * 4), dim3(NT), 0, stream>>>(k, v, prep, out);
  eco_attn_kernel<<<dim3(NJG, NB), dim3(NT), 0, stream>>>(q, prep, out);
}

// Round 2
// 116.407 us; speedup vs baseline: 1.0747x; 1.0747x over previous
//
#include <hip/hip_runtime.h>
#include <cstdint>
#include <cstddef>

// EcoAttention: block-local top-p truncated attention, S=4096 D=128 BLOCK=64.
//
// R12 = R10 + bounded hybrid top-p + PV high-half skip.
//  - Hybrid t: branch-free 4-step max-peel (positions 0..4 of the sorted
//    order; position 0 is free since max exp == 1.0). Rows crossing within
//    5 positions (typical: t in 0..3) are decided. Only if __any(live)
//    (wave-uniform, rare-ish) run R10's exact bitonic on the zero-removed
//    array with the cumsum offset by the peeled prefix -> exact t always.
//    R11's unbounded while-loop peel was latency/straggler-bound and added
//    spill traffic; this version is fixed-trip and fully unrolled.
//  - tmax = wave-max(t) (4 int shuffles): when tmax <= 32 (essentially
//    always), weight chunks for K 32..63 are all zero -> skip the ks2=1
//    half of PV (8 of 16 MFMAs + 8 Vt loads) and the nt>=2 weight emission.
//  - MFMA(K,Q): C col(=lane&15) is the Q-row -> each lane holds 16 scores of
//    ONE Q-row (K idx = nt*16+quad*4+rg). Peel/sort run register-direct.
//  - LDS = 32KB K-planes + 8KB weight scratch = 40KB -> 4 WG/CU; grid
//    1024 = exactly 4/CU, no tail; __launch_bounds__(256,4).
//  - prep: LDS-free, 256 WGs (coalesced K-split + Vt-frag emission +
//    distributed O zeroing).

#define SEQ   4096
#define DIM   128
#define BLK   64
#define NB    (SEQ / BLK)   // 64
#define NJG   16            // j-groups (1024 WGs)
#define JPB   (NB / NJG)    // 4 key blocks per WG
#define NT    256
#define PSTR  12288         // uints per prepped block (Khi 16KB | Kr 16KB | Vt 16KB)
#define THRESH 0.95f
#define EPSF   1e-8f

typedef __attribute__((ext_vector_type(8))) _Float16 f16x8;
typedef __attribute__((ext_vector_type(4))) float    f32x4;

#define MFMAH(a, b, c) __builtin_amdgcn_mfma_f32_16x16x32_f16((a), (b), (c), 0, 0, 0)

union UH4 { uint2 u; _Float16 h[4]; };
union UH8 { uint4 u; f16x8 v; };

__device__ __forceinline__ void gll16(const uint* g, uint* l) {
  __builtin_amdgcn_global_load_lds(
      (const __attribute__((address_space(1))) void*)g,
      (__attribute__((address_space(3))) void*)l, 16, 0, 0);
}

// ---- prep: LDS-free, 4 WGs per key block. Builds [Khi|Kr|Vt-frag] 48KB
//      images in d_ws and zeroes O. ----
__global__ __launch_bounds__(NT, 4) void eco_prep_kernel(
    const float* __restrict__ K, const float* __restrict__ V,
    uint* __restrict__ P, float* __restrict__ O) {
  const int tid  = threadIdx.x;
  const int b    = blockIdx.x;     // 0..255
  const int jb   = b >> 2;
  const int part = b & 3;

  // zero O slice (2MB spread over 256 WGs)
  {
    float4 z = {0.f, 0.f, 0.f, 0.f};
    float4* op = (float4*)O;
#pragma unroll
    for (int it = 0; it < 2; ++it) op[b * 512 + it * NT + tid] = z;
  }

  // K 2-term f16 split -> swizzled planes (element (r,c): chunk=c/8,
  // uint off r*64 + ((chunk ^ (r&15))*4) + (c%8)/2); 2048 float4 per block.
  {
    const float4* gk = (const float4*)(K + (size_t)jb * BLK * DIM);
    uint* dst = P + (size_t)jb * PSTR;
#pragma unroll
    for (int it = 0; it < 2; ++it) {
      int f = part * 512 + it * NT + tid;   // float4 idx 0..2047
      int r = f >> 5, c4 = f & 31;
      float4 x = gk[f];
      float xs[4] = {x.x, x.y, x.z, x.w};
      UH4 uh, ur;
#pragma unroll
      for (int e = 0; e < 4; ++e) {
        float v = xs[e];
        _Float16 h = (_Float16)v;
        uh.h[e] = h;
        ur.h[e] = (_Float16)(v - (float)h);   // exact residual (Sterbenz)
      }
      uint off = (uint)r * 64u + (((uint)(c4 >> 1) ^ (uint)(r & 15)) << 2) +
                 (uint)((c4 & 1) << 1);
      *(uint2*)&dst[off]        = uh.u;
      *(uint2*)&dst[4096 + off] = ur.u;
    }
  }

  // Vt in PV B-frag linear order: ONLY 1024 fragments (ch in [0,8), d in
  // [0,128)); frag idx = ch*128 + d, 8 f16 = V[ch*8+j][d]. One frag/thread.
  {
    const float* gv = V + (size_t)jb * BLK * DIM;
    uint4* dv = (uint4*)(P + (size_t)jb * PSTR + 8192);
    int idx = part * 256 + tid;            // frag idx 0..1023
    int ch = idx >> 7, d = idx & 127;
    UH8 u;
#pragma unroll
    for (int j = 0; j < 8; ++j)
      u.v[j] = (_Float16)gv[(ch * 8 + j) * DIM + d];
    dv[idx] = u.u;
  }
}

// lane-uniform-direction compare-exchange (desc if d)
#define CE(x, y, dmax) { float _hi = fmaxf((x), (y)); float _lo = fminf((x), (y)); \
                         (x) = (dmax) ? _hi : _lo; (y) = (dmax) ? _lo : _hi; }

__global__ __launch_bounds__(NT, 4) void eco_attn_kernel(
    const float* __restrict__ Q, const uint* __restrict__ P,
    float* __restrict__ O) {
  __shared__ __align__(16) uint sK[8192];   // 32 KB: Khi / Kr planes
  __shared__ __align__(16) uint sW[2048];   // 8 KB: 4 x (16 rows x 32 uints)

  const int tid  = threadIdx.x;
  const int ib   = blockIdx.y;
  const int jg   = blockIdx.x;
  const int lane = tid & 63;
  const int wv   = tid >> 6;
  const int quad = lane >> 4;   // 0..3
  const int l16  = lane & 15;
  const int q4   = quad << 2;

  uint* sWw = sW + wv * 512;    // this wave's weight rows (16 x 32 uints)

  // ---- Q fragments (B-operand now): q-row = wv*16+l16, k = ks*32+quad*8+j ----
  f16x8 qh[4], qr[4];
  {
    const float* qp = Q + (size_t)(ib * BLK + wv * 16 + l16) * DIM + quad * 8;
#pragma unroll
    for (int ks = 0; ks < 4; ++ks) {
      float4 x0 = *(const float4*)(qp + ks * 32);
      float4 x1 = *(const float4*)(qp + ks * 32 + 4);
      float xs[8] = {x0.x, x0.y, x0.z, x0.w, x1.x, x1.y, x1.z, x1.w};
      f16x8 h8, r8;
#pragma unroll
      for (int e = 0; e < 8; ++e) {
        float v = xs[e];
        _Float16 h = (_Float16)v;
        h8[e] = h;
        r8[e] = (_Float16)(v - (float)h);
      }
      qh[ks] = h8; qr[ks] = r8;
    }
  }

  const f32x4 zf = {0.f, 0.f, 0.f, 0.f};
  f32x4 pv[8];
#pragma unroll
  for (int i = 0; i < 8; ++i) pv[i] = zf;

  // prologue: stage first K image (32KB = 8 x 16B per thread)
  {
    const uint* gsrc = P + (size_t)(jg * JPB) * PSTR;
#pragma unroll
    for (int it = 0; it < 8; ++it) {
      int idx = (it * NT + tid) << 2;
      gll16(gsrc + idx, sK + idx);
    }
  }

  for (int jj = 0; jj < JPB; ++jj) {
    const int jb = jg * JPB + jj;
    __syncthreads();  // B1: K image staged (vmcnt drained by barrier)

    // ---- QK^T, operand-swapped: A = K (from LDS), B = Q (resident) ----
    // C: col(l16) = Q-row (wv*16+l16), row(quad*4+reg) = K-row nt*16+quad*4+reg
    f32x4 ah[4], ar[4];
#pragma unroll
    for (int nt = 0; nt < 4; ++nt) { ah[nt] = zf; ar[nt] = zf; }
#pragma unroll
    for (int nt = 0; nt < 4; ++nt) {
      const int rB = nt * 16 + l16;      // K-row for the A-frag read
      const uint rowoff = (uint)rB * 64u;
      const uint swk = (uint)(rB & 15);
#pragma unroll
      for (int ks = 0; ks < 4; ++ks) {
        uint off = rowoff + ((((uint)(ks * 4 + quad)) ^ swk) << 2);
        f16x8 bh = *(const f16x8*)&sK[off];
        f16x8 br = *(const f16x8*)&sK[4096 + off];
        ah[nt] = MFMAH(bh, qh[ks], ah[nt]);
        ar[nt] = MFMAH(br, qh[ks], ar[nt]);
        ar[nt] = MFMAH(bh, qr[ks], ar[nt]);
      }
    }
    __syncthreads();  // B0: all waves done reading sK

    // ---- prefetch next K image (overlaps top-p + PV below) ----
    if (jj + 1 < JPB) {
      const uint* gsrc = P + (size_t)(jb + 1) * PSTR;
#pragma unroll
      for (int it = 0; it < 8; ++it) {
        int idx = (it * NT + tid) << 2;
        gll16(gsrc + idx, sK + idx);
      }
    }

    bool doHi;  // does PV need the K 32..63 half?

    // ---- top-p softmax, register-direct: this lane owns Q-row wv*16+l16;
    //      a[i] (i = nt*4+rg) is score at K-index nt*16 + q4 + rg ----
    {
      float a[16], e[16];
#pragma unroll
      for (int nt = 0; nt < 4; ++nt) {
        f32x4 sc = ah[nt] + ar[nt];
#pragma unroll
        for (int rg = 0; rg < 4; ++rg) a[nt * 4 + rg] = sc[rg];
      }
      // row max: local tree + cross-quad (lanes l16, l16+16, +32, +48)
      float mt[8];
#pragma unroll
      for (int i = 0; i < 8; ++i) mt[i] = fmaxf(a[i], a[i + 8]);
#pragma unroll
      for (int w2 = 4; w2 >= 1; w2 >>= 1)
#pragma unroll
        for (int i = 0; i < w2; ++i) mt[i] = fmaxf(mt[i], mt[i + w2]);
      float m = mt[0];
      m = fmaxf(m, __shfl_xor(m, 16, 64));
      m = fmaxf(m, __shfl_xor(m, 32, 64));
#pragma unroll
      for (int i = 0; i < 16; ++i) { a[i] = __expf(a[i] - m); e[i] = a[i]; }
      float st[8];
#pragma unroll
      for (int i = 0; i < 8; ++i) st[i] = a[i] + a[i + 8];
#pragma unroll
      for (int w2 = 4; w2 >= 1; w2 >>= 1)
#pragma unroll
        for (int i = 0; i < w2; ++i) st[i] += st[i + w2];
      float sr = st[0];
      sr += __shfl_xor(sr, 16, 64);
      sr += __shfl_xor(sr, 32, 64);
      const float T = THRESH * sr;

      // ---- branch-free 4-step max-peel (sorted positions 0..4).
      //      Position 0 is free: the max exp is exactly 1.0f.
      float cum = 1.0f;
      bool live = (cum < T);
      int t = live ? 1 : 0;
#pragma unroll
      for (int i = 0; i < 16; ++i) a[i] = (a[i] >= 1.0f) ? 0.f : a[i];
#pragma unroll
      for (int p4 = 0; p4 < 4; ++p4) {
        float M = fmaxf(fmaxf(fmaxf(a[0], a[1]), a[2]),
                        fmaxf(fmaxf(a[3], a[4]), a[5]));
        M = fmaxf(M, fmaxf(fmaxf(a[6],  a[7]),  a[8]));
        M = fmaxf(M, fmaxf(fmaxf(a[9],  a[10]), a[11]));
        M = fmaxf(M, fmaxf(fmaxf(a[12], a[13]), a[14]));
        M = fmaxf(M, a[15]);
        M = fmaxf(M, __shfl_xor(M, 16, 64));
        M = fmaxf(M, __shfl_xor(M, 32, 64));
        const float cn = cum + M;
        const bool cross = !(cn < T) || !(M > 0.f);
        if (live) { cum = cn; t += cross ? 0 : 1; }
        live = live && !cross;
#pragma unroll
        for (int i = 0; i < 16; ++i) a[i] = (a[i] >= M) ? 0.f : a[i];
      }

      // ---- rare exact fallback: bitonic sort of remaining values (peeled
      //      slots are 0, sort to the tail), cumsum offset by peeled prefix.
      if (__any(live)) {
        const int s = quad;
#pragma unroll
        for (int k2 = 2; k2 <= 8; k2 <<= 1)
#pragma unroll
          for (int j2 = k2 >> 1; j2 >= 1; j2 >>= 1)
#pragma unroll
            for (int i = 0; i < 16; ++i) {
              int l = i ^ j2;
              if (l > i) { bool d = ((i & k2) == 0); CE(a[i], a[l], d); }
            }
        const bool x16 = ((s & 1) == 0);
        const bool x32 = ((s & 2) == 0);
#pragma unroll
        for (int j2 = 8; j2 >= 1; j2 >>= 1)
#pragma unroll
          for (int i = 0; i < 16; ++i) {
            int l = i ^ j2;
            if (l > i) { CE(a[i], a[l], x16); }
          }
        {
          const bool km = (x32 == x16);
#pragma unroll
          for (int i = 0; i < 16; ++i) {
            float o = __shfl_xor(a[i], 16, 64);
            a[i] = km ? fmaxf(a[i], o) : fminf(a[i], o);
          }
#pragma unroll
          for (int j2 = 8; j2 >= 1; j2 >>= 1)
#pragma unroll
            for (int i = 0; i < 16; ++i) {
              int l = i ^ j2;
              if (l > i) { CE(a[i], a[l], x32); }
            }
        }
        {
#pragma unroll
          for (int i = 0; i < 16; ++i) {
            float o = __shfl_xor(a[i], 32, 64);
            a[i] = x32 ? fmaxf(a[i], o) : fminf(a[i], o);
          }
#pragma unroll
          for (int i = 0; i < 16; ++i) {
            float o = __shfl_xor(a[i], 16, 64);
            a[i] = x16 ? fmaxf(a[i], o) : fminf(a[i], o);
          }
#pragma unroll
          for (int j2 = 8; j2 >= 1; j2 >>= 1)
#pragma unroll
            for (int i = 0; i < 16; ++i) {
              int l = i ^ j2;
              if (l > i) { CE(a[i], a[l], true); }
            }
        }
        // global inclusive cumsum over the remaining sorted values
#pragma unroll
        for (int i = 1; i < 16; ++i) a[i] += a[i - 1];
        float tot = a[15];
        float c = tot;
        float o1 = __shfl_up(c, 16, 64); if (s >= 1) c += o1;
        float o2 = __shfl_up(c, 32, 64); if (s >= 2) c += o2;
        const float excl = c - tot;
        int cnt = 0;
#pragma unroll
        for (int i = 0; i < 16; ++i) cnt += ((cum + a[i] + excl) < T) ? 1 : 0;
        cnt += __shfl_xor(cnt, 16, 64);
        cnt += __shfl_xor(cnt, 32, 64);
        if (live) t += cnt;
      }

      // wave-max of t (t is quad-uniform; reduce over the 16 l16 rows)
      {
        int tm = t;
        int o;
        o = __shfl_xor(tm, 1, 64); tm = (o > tm) ? o : tm;
        o = __shfl_xor(tm, 2, 64); tm = (o > tm) ? o : tm;
        o = __shfl_xor(tm, 4, 64); tm = (o > tm) ? o : tm;
        o = __shfl_xor(tm, 8, 64); tm = (o > tm) ? o : tm;
        doHi = (tm > 32);
      }

      // renormalize first-t (ORIGINAL K order; kidx = nt*16 + q4 + rg)
      float p = 0.f;
#pragma unroll
      for (int i = 0; i < 16; ++i) {
        int kidx = ((i >> 2) << 4) + q4 + (i & 3);
        p += (kidx < t) ? e[i] : 0.f;
      }
      p += __shfl_xor(p, 16, 64);
      p += __shfl_xor(p, 32, 64);
      const float rn = 1.0f / (p + EPSF);
      // emit f16 weights: row l16, 16 chunks of 4 f16; chunk c4 = nt*4+quad
      // at swizzled uint offset row*32 + ((c4 ^ row) << 1)
      uint* wrow = sWw + l16 * 32;
#pragma unroll
      for (int nt = 0; nt < 2; ++nt) {
        UH4 u;
#pragma unroll
        for (int rg = 0; rg < 4; ++rg) {
          int kidx = nt * 16 + q4 + rg;
          float w = (kidx < t) ? e[nt * 4 + rg] * rn : 0.f;
          u.h[rg] = (_Float16)w;
        }
        uint c4 = (uint)(nt * 4 + quad);
        *(uint2*)&wrow[(c4 ^ (uint)l16) << 1] = u.u;
      }
      if (doHi) {
#pragma unroll
        for (int nt = 2; nt < 4; ++nt) {
          UH4 u;
#pragma unroll
          for (int rg = 0; rg < 4; ++rg) {
            int kidx = nt * 16 + q4 + rg;
            float w = (kidx < t) ? e[nt * 4 + rg] * rn : 0.f;
            u.h[rg] = (_Float16)w;
          }
          uint c4 = (uint)(nt * 4 + quad);
          *(uint2*)&wrow[(c4 ^ (uint)l16) << 1] = u.u;
        }
      }
    }
    __builtin_amdgcn_wave_barrier();  // weight writes before A-frag reads

    // ---- PV: A = f16 weights (wave-private LDS), B = Vt-frag from global ----
    // ks2=0 covers K 0..31 (always); ks2=1 covers K 32..63 (only if doHi).
    const uint* gvt = P + (size_t)jb * PSTR + 8192;
    {
      uint c0 = (uint)(quad * 2);
      const uint* wrow = sWw + l16 * 32;
      uint2 lo = *(const uint2*)&wrow[(c0 ^ (uint)l16) << 1];
      uint2 hi = *(const uint2*)&wrow[((c0 + 1) ^ (uint)l16) << 1];
      UH8 u;
      u.u = make_uint4(lo.x, lo.y, hi.x, hi.y);
      f16x8 wf0 = u.v;
#pragma unroll
      for (int nt2 = 0; nt2 < 8; ++nt2) {
        f16x8 vf = *(const f16x8*)&gvt[((uint)(quad * 128 +
                                               nt2 * 16 + l16)) << 2];
        pv[nt2] = MFMAH(wf0, vf, pv[nt2]);
      }
    }
    if (doHi) {
      uint c0 = (uint)(8 + quad * 2);
      const uint* wrow = sWw + l16 * 32;
      uint2 lo = *(const uint2*)&wrow[(c0 ^ (uint)l16) << 1];
      uint2 hi = *(const uint2*)&wrow[((c0 + 1) ^ (uint)l16) << 1];
      UH8 u;
      u.u = make_uint4(lo.x, lo.y, hi.x, hi.y);
      f16x8 wf1 = u.v;
#pragma unroll
      for (int nt2 = 0; nt2 < 8; ++nt2) {
        f16x8 vf = *(const f16x8*)&gvt[((uint)((4 + quad) * 128 +
                                               nt2 * 16 + l16)) << 2];
        pv[nt2] = MFMAH(wf1, vf, pv[nt2]);
      }
    }
  }

  // ---- epilogue: C-layout -> global atomicAdd over the 16 j-groups ----
#pragma unroll
  for (int nt2 = 0; nt2 < 8; ++nt2) {
    const int col  = nt2 * 16 + l16;
    const int row0 = ib * BLK + wv * 16 + quad * 4;
#pragma unroll
    for (int rg = 0; rg < 4; ++rg)
      atomicAdd(O + (size_t)(row0 + rg) * DIM + col, pv[nt2][rg]);
  }
}

extern "C" void kernel_launch(void* const* d_in, const int* in_sizes, int n_in,
                              void* d_out, int out_size, void* d_ws, size_t ws_size,
                              hipStream_t stream) {
  (void)in_sizes; (void)n_in; (void)ws_size; (void)out_size;
  const float* q = (const float*)d_in[0];
  const float* k = (const float*)d_in[1];
  const float* v = (const float*)d_in[2];
  float* out = (float*)d_out;
  uint* prep = (uint*)d_ws;   // 64 blocks x 48 KB = 3 MB

  eco_prep_kernel<<<dim3(NB * 4), dim3(NT), 0, stream>>>(k, v, prep, out);
  eco_attn_kernel<<<dim3(NJG, NB), dim3(NT), 0, stream>>>(q, prep, out);
}

// Round 3
// 114.900 us; speedup vs baseline: 1.0888x; 1.0131x over previous
//
#include <hip/hip_runtime.h>
#include <cstdint>
#include <cstddef>

// EcoAttention: block-local top-p truncated attention, S=4096 D=128 BLOCK=64.
//
// R13 = R12 with the atomic epilogue replaced by partial-buffer + reduce.
//  - Theory: 8.4M device-scope f32 atomicAdds (16 WGs x same 32KB O slice,
//    cross-XCD -> memory-side RMW) are the ~45us floor that kept attn at
//    64us across R10 (sort) / R12 (peel) despite -17pt VALUBusy. Replace
//    with plain stores of per-jg partials (32MB streamed) + a reduce
//    kernel (read 32MB + write 2MB ~ 7us). ws guard: falls back to the
//    proven atomic path if ws_size < 36.7MB.
//  - prep distributed over 1024 WGs (4x) to cut its tail.
//  - Hybrid t (R12): branch-free 4-step max-peel + rare exact bitonic
//    fallback; tmax<=32 skips the K 32..63 half of PV.
//  - MFMA(K,Q): C col(=lane&15) is the Q-row -> each lane holds 16 scores of
//    ONE Q-row (K idx = nt*16+quad*4+rg). Peel/sort run register-direct.
//  - LDS = 32KB K-planes + 8KB weight scratch = 40KB -> 4 WG/CU; grid
//    1024 = exactly 4/CU, no tail; __launch_bounds__(256,4).

#define SEQ   4096
#define DIM   128
#define BLK   64
#define NB    (SEQ / BLK)   // 64
#define NJG   16            // j-groups (1024 WGs)
#define JPB   (NB / NJG)    // 4 key blocks per WG
#define NT    256
#define PSTR  12288         // uints per prepped block (Khi 16KB | Kr 16KB | Vt 16KB)
#define THRESH 0.95f
#define EPSF   1e-8f
#define PPART  (PSTR * NB)          // uints of P image  (3 MB)
#define PARTF  (NJG * SEQ * DIM)    // floats of partials (32 MB)
#define WS_NEED ((size_t)PPART * 4 + (size_t)PARTF * 4)

typedef __attribute__((ext_vector_type(8))) _Float16 f16x8;
typedef __attribute__((ext_vector_type(4))) float    f32x4;

#define MFMAH(a, b, c) __builtin_amdgcn_mfma_f32_16x16x32_f16((a), (b), (c), 0, 0, 0)

union UH4 { uint2 u; _Float16 h[4]; };
union UH8 { uint4 u; f16x8 v; };

__device__ __forceinline__ void gll16(const uint* g, uint* l) {
  __builtin_amdgcn_global_load_lds(
      (const __attribute__((address_space(1))) void*)g,
      (__attribute__((address_space(3))) void*)l, 16, 0, 0);
}

// ---- prep: LDS-free, 16 WGs per key block (1024 WGs). Builds
//      [Khi|Kr|Vt-frag] 48KB images in d_ws and zeroes O. ----
__global__ __launch_bounds__(NT, 4) void eco_prep_kernel(
    const float* __restrict__ K, const float* __restrict__ V,
    uint* __restrict__ P, float* __restrict__ O) {
  const int tid = threadIdx.x;
  const int w   = blockIdx.x;      // 0..1023
  const int jb  = w >> 4;
  const int sub = w & 15;

  if (tid < 128) {
    // zero O slice (2MB over 1024 WGs x 128 float4)
    float4 z = {0.f, 0.f, 0.f, 0.f};
    ((float4*)O)[w * 128 + tid] = z;

    // K 2-term f16 split -> swizzled planes (element (r,c): chunk=c/8,
    // uint off r*64 + ((chunk ^ (r&15))*4) + (c%8)/2); 2048 float4 per block.
    const float4* gk = (const float4*)(K + (size_t)jb * BLK * DIM);
    uint* dst = P + (size_t)jb * PSTR;
    int f = sub * 128 + tid;        // float4 idx 0..2047
    int r = f >> 5, c4 = f & 31;
    float4 x = gk[f];
    float xs[4] = {x.x, x.y, x.z, x.w};
    UH4 uh, ur;
#pragma unroll
    for (int e = 0; e < 4; ++e) {
      float v = xs[e];
      _Float16 h = (_Float16)v;
      uh.h[e] = h;
      ur.h[e] = (_Float16)(v - (float)h);   // exact residual (Sterbenz)
    }
    uint off = (uint)r * 64u + (((uint)(c4 >> 1) ^ (uint)(r & 15)) << 2) +
               (uint)((c4 & 1) << 1);
    *(uint2*)&dst[off]        = uh.u;
    *(uint2*)&dst[4096 + off] = ur.u;
  } else if (tid < 192) {
    // Vt in PV B-frag linear order: 1024 fragments (ch in [0,8), d in
    // [0,128)); frag idx = ch*128 + d, 8 f16 = V[ch*8+j][d].
    const float* gv = V + (size_t)jb * BLK * DIM;
    uint4* dv = (uint4*)(P + (size_t)jb * PSTR + 8192);
    int idx = sub * 64 + (tid - 128);   // frag idx 0..1023
    int ch = idx >> 7, d = idx & 127;
    UH8 u;
#pragma unroll
    for (int j = 0; j < 8; ++j)
      u.v[j] = (_Float16)gv[(ch * 8 + j) * DIM + d];
    dv[idx] = u.u;
  }
}

// ---- reduce: O = sum over 16 jg partials. 512 WGs x 256 thr, one float4
//      per thread. ----
__global__ __launch_bounds__(NT) void eco_reduce_kernel(
    const float* __restrict__ Part, float* __restrict__ O) {
  const int gid = blockIdx.x * NT + threadIdx.x;   // 0..131071
  const float4* p4 = (const float4*)Part;
  float4 a = p4[gid];
#pragma unroll
  for (int jg = 1; jg < NJG; ++jg) {
    float4 b = p4[(size_t)jg * (SEQ * DIM / 4) + gid];
    a.x += b.x; a.y += b.y; a.z += b.z; a.w += b.w;
  }
  ((float4*)O)[gid] = a;
}

// lane-uniform-direction compare-exchange (desc if d)
#define CE(x, y, dmax) { float _hi = fmaxf((x), (y)); float _lo = fminf((x), (y)); \
                         (x) = (dmax) ? _hi : _lo; (y) = (dmax) ? _lo : _hi; }

template <bool PARTIAL>
__global__ __launch_bounds__(NT, 4) void eco_attn_kernel(
    const float* __restrict__ Q, const uint* __restrict__ P,
    float* __restrict__ O, float* __restrict__ Part) {
  __shared__ __align__(16) uint sK[8192];   // 32 KB: Khi / Kr planes
  __shared__ __align__(16) uint sW[2048];   // 8 KB: 4 x (16 rows x 32 uints)

  const int tid  = threadIdx.x;
  const int ib   = blockIdx.y;
  const int jg   = blockIdx.x;
  const int lane = tid & 63;
  const int wv   = tid >> 6;
  const int quad = lane >> 4;   // 0..3
  const int l16  = lane & 15;
  const int q4   = quad << 2;

  uint* sWw = sW + wv * 512;    // this wave's weight rows (16 x 32 uints)

  // ---- Q fragments (B-operand now): q-row = wv*16+l16, k = ks*32+quad*8+j ----
  f16x8 qh[4], qr[4];
  {
    const float* qp = Q + (size_t)(ib * BLK + wv * 16 + l16) * DIM + quad * 8;
#pragma unroll
    for (int ks = 0; ks < 4; ++ks) {
      float4 x0 = *(const float4*)(qp + ks * 32);
      float4 x1 = *(const float4*)(qp + ks * 32 + 4);
      float xs[8] = {x0.x, x0.y, x0.z, x0.w, x1.x, x1.y, x1.z, x1.w};
      f16x8 h8, r8;
#pragma unroll
      for (int e = 0; e < 8; ++e) {
        float v = xs[e];
        _Float16 h = (_Float16)v;
        h8[e] = h;
        r8[e] = (_Float16)(v - (float)h);
      }
      qh[ks] = h8; qr[ks] = r8;
    }
  }

  const f32x4 zf = {0.f, 0.f, 0.f, 0.f};
  f32x4 pv[8];
#pragma unroll
  for (int i = 0; i < 8; ++i) pv[i] = zf;

  // prologue: stage first K image (32KB = 8 x 16B per thread)
  {
    const uint* gsrc = P + (size_t)(jg * JPB) * PSTR;
#pragma unroll
    for (int it = 0; it < 8; ++it) {
      int idx = (it * NT + tid) << 2;
      gll16(gsrc + idx, sK + idx);
    }
  }

  for (int jj = 0; jj < JPB; ++jj) {
    const int jb = jg * JPB + jj;
    __syncthreads();  // B1: K image staged (vmcnt drained by barrier)

    // ---- QK^T, operand-swapped: A = K (from LDS), B = Q (resident) ----
    // C: col(l16) = Q-row (wv*16+l16), row(quad*4+reg) = K-row nt*16+quad*4+reg
    f32x4 ah[4], ar[4];
#pragma unroll
    for (int nt = 0; nt < 4; ++nt) { ah[nt] = zf; ar[nt] = zf; }
#pragma unroll
    for (int nt = 0; nt < 4; ++nt) {
      const int rB = nt * 16 + l16;      // K-row for the A-frag read
      const uint rowoff = (uint)rB * 64u;
      const uint swk = (uint)(rB & 15);
#pragma unroll
      for (int ks = 0; ks < 4; ++ks) {
        uint off = rowoff + ((((uint)(ks * 4 + quad)) ^ swk) << 2);
        f16x8 bh = *(const f16x8*)&sK[off];
        f16x8 br = *(const f16x8*)&sK[4096 + off];
        ah[nt] = MFMAH(bh, qh[ks], ah[nt]);
        ar[nt] = MFMAH(br, qh[ks], ar[nt]);
        ar[nt] = MFMAH(bh, qr[ks], ar[nt]);
      }
    }
    __syncthreads();  // B0: all waves done reading sK

    // ---- prefetch next K image (overlaps top-p + PV below) ----
    if (jj + 1 < JPB) {
      const uint* gsrc = P + (size_t)(jb + 1) * PSTR;
#pragma unroll
      for (int it = 0; it < 8; ++it) {
        int idx = (it * NT + tid) << 2;
        gll16(gsrc + idx, sK + idx);
      }
    }

    bool doHi;  // does PV need the K 32..63 half?

    // ---- top-p softmax, register-direct: this lane owns Q-row wv*16+l16;
    //      a[i] (i = nt*4+rg) is score at K-index nt*16 + q4 + rg ----
    {
      float a[16], e[16];
#pragma unroll
      for (int nt = 0; nt < 4; ++nt) {
        f32x4 sc = ah[nt] + ar[nt];
#pragma unroll
        for (int rg = 0; rg < 4; ++rg) a[nt * 4 + rg] = sc[rg];
      }
      // row max: local tree + cross-quad (lanes l16, l16+16, +32, +48)
      float mt[8];
#pragma unroll
      for (int i = 0; i < 8; ++i) mt[i] = fmaxf(a[i], a[i + 8]);
#pragma unroll
      for (int w2 = 4; w2 >= 1; w2 >>= 1)
#pragma unroll
        for (int i = 0; i < w2; ++i) mt[i] = fmaxf(mt[i], mt[i + w2]);
      float m = mt[0];
      m = fmaxf(m, __shfl_xor(m, 16, 64));
      m = fmaxf(m, __shfl_xor(m, 32, 64));
#pragma unroll
      for (int i = 0; i < 16; ++i) { a[i] = __expf(a[i] - m); e[i] = a[i]; }
      float st[8];
#pragma unroll
      for (int i = 0; i < 8; ++i) st[i] = a[i] + a[i + 8];
#pragma unroll
      for (int w2 = 4; w2 >= 1; w2 >>= 1)
#pragma unroll
        for (int i = 0; i < w2; ++i) st[i] += st[i + w2];
      float sr = st[0];
      sr += __shfl_xor(sr, 16, 64);
      sr += __shfl_xor(sr, 32, 64);
      const float T = THRESH * sr;

      // ---- branch-free 4-step max-peel (sorted positions 0..4).
      //      Position 0 is free: the max exp is exactly 1.0f.
      float cum = 1.0f;
      bool live = (cum < T);
      int t = live ? 1 : 0;
#pragma unroll
      for (int i = 0; i < 16; ++i) a[i] = (a[i] >= 1.0f) ? 0.f : a[i];
#pragma unroll
      for (int p4 = 0; p4 < 4; ++p4) {
        float M = fmaxf(fmaxf(fmaxf(a[0], a[1]), a[2]),
                        fmaxf(fmaxf(a[3], a[4]), a[5]));
        M = fmaxf(M, fmaxf(fmaxf(a[6],  a[7]),  a[8]));
        M = fmaxf(M, fmaxf(fmaxf(a[9],  a[10]), a[11]));
        M = fmaxf(M, fmaxf(fmaxf(a[12], a[13]), a[14]));
        M = fmaxf(M, a[15]);
        M = fmaxf(M, __shfl_xor(M, 16, 64));
        M = fmaxf(M, __shfl_xor(M, 32, 64));
        const float cn = cum + M;
        const bool cross = !(cn < T) || !(M > 0.f);
        if (live) { cum = cn; t += cross ? 0 : 1; }
        live = live && !cross;
#pragma unroll
        for (int i = 0; i < 16; ++i) a[i] = (a[i] >= M) ? 0.f : a[i];
      }

      // ---- rare exact fallback: bitonic sort of remaining values (peeled
      //      slots are 0, sort to the tail), cumsum offset by peeled prefix.
      if (__any(live)) {
        const int s = quad;
#pragma unroll
        for (int k2 = 2; k2 <= 8; k2 <<= 1)
#pragma unroll
          for (int j2 = k2 >> 1; j2 >= 1; j2 >>= 1)
#pragma unroll
            for (int i = 0; i < 16; ++i) {
              int l = i ^ j2;
              if (l > i) { bool d = ((i & k2) == 0); CE(a[i], a[l], d); }
            }
        const bool x16 = ((s & 1) == 0);
        const bool x32 = ((s & 2) == 0);
#pragma unroll
        for (int j2 = 8; j2 >= 1; j2 >>= 1)
#pragma unroll
          for (int i = 0; i < 16; ++i) {
            int l = i ^ j2;
            if (l > i) { CE(a[i], a[l], x16); }
          }
        {
          const bool km = (x32 == x16);
#pragma unroll
          for (int i = 0; i < 16; ++i) {
            float o = __shfl_xor(a[i], 16, 64);
            a[i] = km ? fmaxf(a[i], o) : fminf(a[i], o);
          }
#pragma unroll
          for (int j2 = 8; j2 >= 1; j2 >>= 1)
#pragma unroll
            for (int i = 0; i < 16; ++i) {
              int l = i ^ j2;
              if (l > i) { CE(a[i], a[l], x32); }
            }
        }
        {
#pragma unroll
          for (int i = 0; i < 16; ++i) {
            float o = __shfl_xor(a[i], 32, 64);
            a[i] = x32 ? fmaxf(a[i], o) : fminf(a[i], o);
          }
#pragma unroll
          for (int i = 0; i < 16; ++i) {
            float o = __shfl_xor(a[i], 16, 64);
            a[i] = x16 ? fmaxf(a[i], o) : fminf(a[i], o);
          }
#pragma unroll
          for (int j2 = 8; j2 >= 1; j2 >>= 1)
#pragma unroll
            for (int i = 0; i < 16; ++i) {
              int l = i ^ j2;
              if (l > i) { CE(a[i], a[l], true); }
            }
        }
        // global inclusive cumsum over the remaining sorted values
#pragma unroll
        for (int i = 1; i < 16; ++i) a[i] += a[i - 1];
        float tot = a[15];
        float c = tot;
        float o1 = __shfl_up(c, 16, 64); if (s >= 1) c += o1;
        float o2 = __shfl_up(c, 32, 64); if (s >= 2) c += o2;
        const float excl = c - tot;
        int cnt = 0;
#pragma unroll
        for (int i = 0; i < 16; ++i) cnt += ((cum + a[i] + excl) < T) ? 1 : 0;
        cnt += __shfl_xor(cnt, 16, 64);
        cnt += __shfl_xor(cnt, 32, 64);
        if (live) t += cnt;
      }

      // wave-max of t (t is quad-uniform; reduce over the 16 l16 rows)
      {
        int tm = t;
        int o;
        o = __shfl_xor(tm, 1, 64); tm = (o > tm) ? o : tm;
        o = __shfl_xor(tm, 2, 64); tm = (o > tm) ? o : tm;
        o = __shfl_xor(tm, 4, 64); tm = (o > tm) ? o : tm;
        o = __shfl_xor(tm, 8, 64); tm = (o > tm) ? o : tm;
        doHi = (tm > 32);
      }

      // renormalize first-t (ORIGINAL K order; kidx = nt*16 + q4 + rg)
      float p = 0.f;
#pragma unroll
      for (int i = 0; i < 16; ++i) {
        int kidx = ((i >> 2) << 4) + q4 + (i & 3);
        p += (kidx < t) ? e[i] : 0.f;
      }
      p += __shfl_xor(p, 16, 64);
      p += __shfl_xor(p, 32, 64);
      const float rn = 1.0f / (p + EPSF);
      // emit f16 weights: row l16, 16 chunks of 4 f16; chunk c4 = nt*4+quad
      // at swizzled uint offset row*32 + ((c4 ^ row) << 1)
      uint* wrow = sWw + l16 * 32;
#pragma unroll
      for (int nt = 0; nt < 2; ++nt) {
        UH4 u;
#pragma unroll
        for (int rg = 0; rg < 4; ++rg) {
          int kidx = nt * 16 + q4 + rg;
          float w = (kidx < t) ? e[nt * 4 + rg] * rn : 0.f;
          u.h[rg] = (_Float16)w;
        }
        uint c4 = (uint)(nt * 4 + quad);
        *(uint2*)&wrow[(c4 ^ (uint)l16) << 1] = u.u;
      }
      if (doHi) {
#pragma unroll
        for (int nt = 2; nt < 4; ++nt) {
          UH4 u;
#pragma unroll
          for (int rg = 0; rg < 4; ++rg) {
            int kidx = nt * 16 + q4 + rg;
            float w = (kidx < t) ? e[nt * 4 + rg] * rn : 0.f;
            u.h[rg] = (_Float16)w;
          }
          uint c4 = (uint)(nt * 4 + quad);
          *(uint2*)&wrow[(c4 ^ (uint)l16) << 1] = u.u;
        }
      }
    }
    __builtin_amdgcn_wave_barrier();  // weight writes before A-frag reads

    // ---- PV: A = f16 weights (wave-private LDS), B = Vt-frag from global ----
    // ks2=0 covers K 0..31 (always); ks2=1 covers K 32..63 (only if doHi).
    const uint* gvt = P + (size_t)jb * PSTR + 8192;
    {
      uint c0 = (uint)(quad * 2);
      const uint* wrow = sWw + l16 * 32;
      uint2 lo = *(const uint2*)&wrow[(c0 ^ (uint)l16) << 1];
      uint2 hi = *(const uint2*)&wrow[((c0 + 1) ^ (uint)l16) << 1];
      UH8 u;
      u.u = make_uint4(lo.x, lo.y, hi.x, hi.y);
      f16x8 wf0 = u.v;
#pragma unroll
      for (int nt2 = 0; nt2 < 8; ++nt2) {
        f16x8 vf = *(const f16x8*)&gvt[((uint)(quad * 128 +
                                               nt2 * 16 + l16)) << 2];
        pv[nt2] = MFMAH(wf0, vf, pv[nt2]);
      }
    }
    if (doHi) {
      uint c0 = (uint)(8 + quad * 2);
      const uint* wrow = sWw + l16 * 32;
      uint2 lo = *(const uint2*)&wrow[(c0 ^ (uint)l16) << 1];
      uint2 hi = *(const uint2*)&wrow[((c0 + 1) ^ (uint)l16) << 1];
      UH8 u;
      u.u = make_uint4(lo.x, lo.y, hi.x, hi.y);
      f16x8 wf1 = u.v;
#pragma unroll
      for (int nt2 = 0; nt2 < 8; ++nt2) {
        f16x8 vf = *(const f16x8*)&gvt[((uint)((4 + quad) * 128 +
                                               nt2 * 16 + l16)) << 2];
        pv[nt2] = MFMAH(wf1, vf, pv[nt2]);
      }
    }
  }

  // ---- epilogue ----
  if constexpr (PARTIAL) {
    // plain stores of this WG's 64x128 partial into its jg slice
    float* pb = Part + (size_t)jg * (SEQ * DIM);
    const int row0 = ib * BLK + wv * 16 + quad * 4;
#pragma unroll
    for (int nt2 = 0; nt2 < 8; ++nt2) {
      const int col = nt2 * 16 + l16;
#pragma unroll
      for (int rg = 0; rg < 4; ++rg)
        pb[(size_t)(row0 + rg) * DIM + col] = pv[nt2][rg];
    }
  } else {
    // fallback: atomicAdd over the 16 j-groups
#pragma unroll
    for (int nt2 = 0; nt2 < 8; ++nt2) {
      const int col  = nt2 * 16 + l16;
      const int row0 = ib * BLK + wv * 16 + quad * 4;
#pragma unroll
      for (int rg = 0; rg < 4; ++rg)
        atomicAdd(O + (size_t)(row0 + rg) * DIM + col, pv[nt2][rg]);
    }
  }
}

extern "C" void kernel_launch(void* const* d_in, const int* in_sizes, int n_in,
                              void* d_out, int out_size, void* d_ws, size_t ws_size,
                              hipStream_t stream) {
  (void)in_sizes; (void)n_in; (void)out_size;
  const float* q = (const float*)d_in[0];
  const float* k = (const float*)d_in[1];
  const float* v = (const float*)d_in[2];
  float* out = (float*)d_out;
  uint* prep = (uint*)d_ws;                                   // 3 MB P images
  float* part = (float*)((char*)d_ws + (size_t)PPART * 4);    // 32 MB partials

  eco_prep_kernel<<<dim3(NB * 16), dim3(NT), 0, stream>>>(k, v, prep, out);
  if (ws_size >= WS_NEED) {
    eco_attn_kernel<true><<<dim3(NJG, NB), dim3(NT), 0, stream>>>(q, prep, out, part);
    eco_reduce_kernel<<<dim3(SEQ * DIM / 4 / NT), dim3(NT), 0, stream>>>(part, out);
  } else {
    eco_attn_kernel<false><<<dim3(NJG, NB), dim3(NT), 0, stream>>>(q, prep, out, nullptr);
  }
}